// Round 2
// baseline (1657.881 us; speedup 1.0000x reference)
//
#include <hip/hip_runtime.h>

#define D 128
#define LN_EPS 1e-5f

static constexpr int cN0 = 20000,  cE0 = 100000;
static constexpr int cN1 = 100000, cE1 = 400000;
static constexpr int cN2 = 400000, cE2 = 800000;

typedef _Float16 f16;
typedef _Float16 f16x8 __attribute__((ext_vector_type(8)));
typedef float f32x4 __attribute__((ext_vector_type(4)));
typedef unsigned short u16x8 __attribute__((ext_vector_type(8)));

// ---------------- f16 helpers ----------------
__device__ inline float h2f(unsigned short u) {
    return (float)__builtin_bit_cast(_Float16, u);
}
__device__ inline unsigned short f2h(float f) {
    return __builtin_bit_cast(unsigned short, (_Float16)f);
}

// ---------------- CSR / degree build ----------------

__global__ void k_count(const int* __restrict__ src, const int* __restrict__ dst,
                        int* cnt_out, int* cnt_in, int E) {
    int e = blockIdx.x * blockDim.x + threadIdx.x;
    if (e < E) {
        atomicAdd(&cnt_out[src[e]], 1);
        atomicAdd(&cnt_in[dst[e]], 1);
    }
}

__global__ void k_bsum(const int* __restrict__ cnt, int* bsum, int n) {
    __shared__ int sd[256];
    int t = threadIdx.x;
    int base = blockIdx.x * 1024 + t * 4;
    int s = 0;
#pragma unroll
    for (int i = 0; i < 4; ++i) { int idx = base + i; if (idx < n) s += cnt[idx]; }
    sd[t] = s; __syncthreads();
    for (int off = 128; off > 0; off >>= 1) {
        if (t < off) sd[t] += sd[t + off];
        __syncthreads();
    }
    if (t == 0) bsum[blockIdx.x] = sd[0];
}

__global__ void k_scan_write(const int* __restrict__ cnt, const int* __restrict__ bsum,
                             int* __restrict__ ptr, int n, int E) {
    __shared__ int sd[256];
    __shared__ int so[256];
    int t = threadIdx.x, blk = blockIdx.x;
    int off = 0;
    for (int i = t; i < blk; i += 256) off += bsum[i];
    so[t] = off; __syncthreads();
    for (int o = 128; o > 0; o >>= 1) { if (t < o) so[t] += so[t + o]; __syncthreads(); }
    int boff = so[0];
    int base = blk * 1024 + t * 4;
    int vals[4]; int s = 0;
#pragma unroll
    for (int i = 0; i < 4; ++i) { int idx = base + i; vals[i] = (idx < n) ? cnt[idx] : 0; s += vals[i]; }
    sd[t] = s; __syncthreads();
    for (int o = 1; o < 256; o <<= 1) {
        int x = (t >= o) ? sd[t - o] : 0;
        __syncthreads();
        sd[t] += x;
        __syncthreads();
    }
    int run = boff + sd[t] - s;
#pragma unroll
    for (int i = 0; i < 4; ++i) {
        int idx = base + i;
        if (idx < n) ptr[idx] = run;
        run += vals[i];
    }
    if (blk == 0 && t == 0) ptr[n] = E;
}

__global__ void k_rin_cursor(const int* __restrict__ cnt_out, const int* __restrict__ cnt_in,
                             const int* __restrict__ ptr, float* __restrict__ rout,
                             float* __restrict__ rin, int* __restrict__ cursor, int n) {
    int i = blockIdx.x * blockDim.x + threadIdx.x;
    if (i < n) {
        rout[i] = rsqrtf((float)(cnt_out[i] + 1));  // +1 self-loop
        rin[i]  = rsqrtf((float)(cnt_in[i] + 1));
        cursor[i] = ptr[i];
    }
}

__global__ void k_fill(const int* __restrict__ src, const int* __restrict__ dst,
                       int* cursor, int* __restrict__ eid, int* __restrict__ srcs, int E) {
    int e = blockIdx.x * blockDim.x + threadIdx.x;
    if (e < E) {
        int p = atomicAdd(&cursor[dst[e]], 1);
        eid[p] = e;
        srcs[p] = src[e];
    }
}

// ---------------- fp32 -> f16 array convert ----------------
__global__ void k_f2h(const float* __restrict__ in, unsigned short* __restrict__ o, int n4) {
    int i = blockIdx.x * 256 + threadIdx.x;
    if (i < n4) {
        float4 v = ((const float4*)in)[i];
        ushort4 u;
        u.x = f2h(v.x); u.y = f2h(v.y); u.z = f2h(v.z); u.w = f2h(v.w);
        ((ushort4*)o)[i] = u;
    }
}

// ---------------- segsum over edge-rows (f16 table -> f16 X) ----------------
__global__ void k_segsum_h(unsigned short* __restrict__ X, const int* __restrict__ ptr,
                           const int* __restrict__ eid, const unsigned short* __restrict__ table,
                           int n) {
    int wid = (blockIdx.x * blockDim.x + threadIdx.x) >> 6;
    int lane = threadIdx.x & 63;
    if (wid >= n) return;
    int j = lane * 2;
    float ax = 0.f, ay = 0.f;
    int p0 = ptr[wid], p1 = ptr[wid + 1];
    for (int p = p0; p < p1; ++p) {
        int e = eid[p];
        ushort2 u = *(const ushort2*)(table + (size_t)e * D + j);
        ax += h2f(u.x); ay += h2f(u.y);
    }
    ushort2 o; o.x = f2h(ax); o.y = f2h(ay);
    *(ushort2*)(X + (size_t)wid * D + j) = o;
}

// ---------------- weight prep: transpose + cw-fold + f16 ----------------
// 7 stage-1 mats [n][k] 128x128:  slots {L0conv, L0td, L1conv, L1bu, L1td, L2conv, L2bu}
// 3 catW^T mats  [n][k] 128x256
__global__ void k_prep_w(const float* __restrict__ convW, const float* __restrict__ fusW,
                         const float* __restrict__ catW,
                         const float* __restrict__ convw, const float* __restrict__ tdw,
                         const float* __restrict__ buw,
                         unsigned short* __restrict__ sWt, unsigned short* __restrict__ kWt) {
    int t = blockIdx.x * 256 + threadIdx.x;
    if (t < 7 * 16384) {
        int slot = t / 16384, r = t % 16384;
        int n = r >> 7, k = r & 127;
        const float* W; const float* cw;
        switch (slot) {
            case 0: W = convW;              cw = convw;            break;  // L0 conv (idx0)
            case 1: W = fusW;               cw = tdw;              break;  // L0 td   (idx0)
            case 2: W = convW + 2 * 16384;  cw = convw + 2 * 128;  break;  // L1 conv (idx2)
            case 3: W = fusW + 2 * 16384;   cw = buw + 2 * 128;    break;  // L1 bu   (idx2)
            case 4: W = fusW + 2 * 16384;   cw = tdw + 2 * 128;    break;  // L1 td   (idx2)
            case 5: W = convW + 1 * 16384;  cw = convw + 1 * 128;  break;  // L2 conv (idx1)
            default: W = fusW + 1 * 16384;  cw = buw + 1 * 128;    break;  // L2 bu   (idx1)
        }
        sWt[t] = f2h(W[k * 128 + n] * cw[n]);
    } else {
        int t2 = t - 7 * 16384;
        if (t2 < 3 * 32768) {
            int mi = t2 / 32768, r = t2 % 32768;
            int n = r >> 8, k = r & 255;
            kWt[mi * 32768 + r] = f2h(catW[mi * 32768 + k * 128 + n]);
        }
    }
}

// ---------------- h-space multi-term aggregation ----------------
// a_t[v] = feat_t[v]*rout[v] + sum_{s->v} feat_t[s]*rout[s]   (self-loop included)
// slot1 may be a gathered feature: feat_1[v] = F1[gidx[v]]
template<int NT, bool G1>
__global__ void k_aggh(const unsigned short* __restrict__ F0,
                       const unsigned short* __restrict__ F1,
                       const unsigned short* __restrict__ F2,
                       const int* __restrict__ gidx,
                       const float* __restrict__ rout,
                       const int* __restrict__ ptr, const int* __restrict__ srcs,
                       unsigned short* __restrict__ A0, unsigned short* __restrict__ A1,
                       unsigned short* __restrict__ A2, int n) {
    int node = (blockIdx.x * blockDim.x + threadIdx.x) >> 5;
    int lane = threadIdx.x & 31;
    if (node >= n) return;
    int j = lane * 4;

    float rt = rout[node];
    float4 a0, a1, a2;
    {
        ushort4 u = *(const ushort4*)(F0 + (size_t)node * D + j);
        a0 = make_float4(h2f(u.x) * rt, h2f(u.y) * rt, h2f(u.z) * rt, h2f(u.w) * rt);
    }
    if (NT > 1) {
        int i1 = G1 ? gidx[node] : node;
        ushort4 u = *(const ushort4*)(F1 + (size_t)i1 * D + j);
        a1 = make_float4(h2f(u.x) * rt, h2f(u.y) * rt, h2f(u.z) * rt, h2f(u.w) * rt);
    }
    if (NT > 2) {
        ushort4 u = *(const ushort4*)(F2 + (size_t)node * D + j);
        a2 = make_float4(h2f(u.x) * rt, h2f(u.y) * rt, h2f(u.z) * rt, h2f(u.w) * rt);
    }

    int p0 = ptr[node], p1 = ptr[node + 1];
    int p = p0;
    // unroll-2: two independent gather chains in flight
    for (; p + 2 <= p1; p += 2) {
        int sA = srcs[p], sB = srcs[p + 1];
        float rA = rout[sA], rB = rout[sB];
        ushort4 uA = *(const ushort4*)(F0 + (size_t)sA * D + j);
        ushort4 uB = *(const ushort4*)(F0 + (size_t)sB * D + j);
        a0.x += h2f(uA.x) * rA + h2f(uB.x) * rB;
        a0.y += h2f(uA.y) * rA + h2f(uB.y) * rB;
        a0.z += h2f(uA.z) * rA + h2f(uB.z) * rB;
        a0.w += h2f(uA.w) * rA + h2f(uB.w) * rB;
        if (NT > 1) {
            int iA = G1 ? gidx[sA] : sA;
            int iB = G1 ? gidx[sB] : sB;
            ushort4 vA = *(const ushort4*)(F1 + (size_t)iA * D + j);
            ushort4 vB = *(const ushort4*)(F1 + (size_t)iB * D + j);
            a1.x += h2f(vA.x) * rA + h2f(vB.x) * rB;
            a1.y += h2f(vA.y) * rA + h2f(vB.y) * rB;
            a1.z += h2f(vA.z) * rA + h2f(vB.z) * rB;
            a1.w += h2f(vA.w) * rA + h2f(vB.w) * rB;
        }
        if (NT > 2) {
            ushort4 vA = *(const ushort4*)(F2 + (size_t)sA * D + j);
            ushort4 vB = *(const ushort4*)(F2 + (size_t)sB * D + j);
            a2.x += h2f(vA.x) * rA + h2f(vB.x) * rB;
            a2.y += h2f(vA.y) * rA + h2f(vB.y) * rB;
            a2.z += h2f(vA.z) * rA + h2f(vB.z) * rB;
            a2.w += h2f(vA.w) * rA + h2f(vB.w) * rB;
        }
    }
    if (p < p1) {
        int sA = srcs[p];
        float rA = rout[sA];
        ushort4 uA = *(const ushort4*)(F0 + (size_t)sA * D + j);
        a0.x += h2f(uA.x) * rA; a0.y += h2f(uA.y) * rA;
        a0.z += h2f(uA.z) * rA; a0.w += h2f(uA.w) * rA;
        if (NT > 1) {
            int iA = G1 ? gidx[sA] : sA;
            ushort4 vA = *(const ushort4*)(F1 + (size_t)iA * D + j);
            a1.x += h2f(vA.x) * rA; a1.y += h2f(vA.y) * rA;
            a1.z += h2f(vA.z) * rA; a1.w += h2f(vA.w) * rA;
        }
        if (NT > 2) {
            ushort4 vA = *(const ushort4*)(F2 + (size_t)sA * D + j);
            a2.x += h2f(vA.x) * rA; a2.y += h2f(vA.y) * rA;
            a2.z += h2f(vA.z) * rA; a2.w += h2f(vA.w) * rA;
        }
    }

    ushort4 o;
    o.x = f2h(a0.x); o.y = f2h(a0.y); o.z = f2h(a0.z); o.w = f2h(a0.w);
    *(ushort4*)(A0 + (size_t)node * D + j) = o;
    if (NT > 1) {
        o.x = f2h(a1.x); o.y = f2h(a1.y); o.z = f2h(a1.z); o.w = f2h(a1.w);
        *(ushort4*)(A1 + (size_t)node * D + j) = o;
    }
    if (NT > 2) {
        o.x = f2h(a2.x); o.y = f2h(a2.y); o.z = f2h(a2.z); o.w = f2h(a2.w);
        *(ushort4*)(A2 + (size_t)node * D + j) = o;
    }
}

// ---------------- mega: per-term GEMM + relu-concat + cat GEMM + LN ----------------
// 64 rows/block, 4 waves x 16 rows. Stage 1: v_t = rin*(a_t @ W't) + b_t*cw_t, K=128.
// relu/sum accumulated in f32 regs; transposed via 32KB XOR-swizzled LDS tile;
// stage 2: (r|s) @ catW^T, K=256; LN epilogue. Weights read from global (L2-broadcast).
template<int NT>
__global__ __launch_bounds__(256) void k_mega(
        const unsigned short* __restrict__ A0h, const unsigned short* __restrict__ A1h,
        const unsigned short* __restrict__ A2h,
        const unsigned short* __restrict__ W0, const unsigned short* __restrict__ W1,
        const unsigned short* __restrict__ W2,
        const float* __restrict__ pb0, const float* __restrict__ pc0,
        const float* __restrict__ pb1, const float* __restrict__ pc1,
        const float* __restrict__ pb2, const float* __restrict__ pc2,
        const float* __restrict__ rin,
        const unsigned short* __restrict__ kWt,
        const float* __restrict__ cbias, const float* __restrict__ gam,
        const float* __restrict__ bet,
        float* __restrict__ out, int M) {
    __shared__ __align__(16) unsigned short tile[64 * 256];   // 32 KiB
    int tid = threadIdx.x;
    int w = tid >> 6, l = tid & 63, g = l >> 4, ln = l & 15;
    int mloc = w * 16 + ln;
    int m = blockIdx.x * 64 + mloc;
    bool vm = m < M;
    float ri = vm ? rin[m] : 0.f;

    f32x4 rr[8] = {};
    f32x4 sv[8] = {};

    const unsigned short* Ah[3] = {A0h, A1h, A2h};
    const unsigned short* Wh[3] = {W0, W1, W2};
    const float* pbs[3] = {pb0, pb1, pb2};
    const float* pcs[3] = {pc0, pc1, pc2};

#pragma unroll
    for (int t = 0; t < NT; ++t) {
        f32x4 acc[8] = {};
        const unsigned short* ap = Ah[t] + (size_t)m * 128;
#pragma unroll
        for (int k0 = 0; k0 < 128; k0 += 32) {
            int kk = k0 + g * 8;
            f16x8 bf = {};
            if (vm) bf = *(const f16x8*)(ap + kk);
#pragma unroll
            for (int nf = 0; nf < 8; ++nf) {
                f16x8 af = *(const f16x8*)(Wh[t] + (size_t)(nf * 16 + ln) * 128 + kk);
                acc[nf] = __builtin_amdgcn_mfma_f32_16x16x32_f16(af, bf, acc[nf], 0, 0, 0);
            }
        }
#pragma unroll
        for (int nf = 0; nf < 8; ++nf) {
            float4 bb = *(const float4*)(pbs[t] + nf * 16 + g * 4);
            float4 cc = *(const float4*)(pcs[t] + nf * 16 + g * 4);
            f32x4 a = acc[nf];
            float v0 = ri * a[0] + bb.x * cc.x;
            float v1 = ri * a[1] + bb.y * cc.y;
            float v2 = ri * a[2] + bb.z * cc.z;
            float v3 = ri * a[3] + bb.w * cc.w;
            rr[nf][0] += fmaxf(v0, 0.f); rr[nf][1] += fmaxf(v1, 0.f);
            rr[nf][2] += fmaxf(v2, 0.f); rr[nf][3] += fmaxf(v3, 0.f);
            sv[nf][0] += v0; sv[nf][1] += v1; sv[nf][2] += v2; sv[nf][3] += v3;
        }
    }

    // write relu-half at k=n, sum-half at k=128+n (row stride 512B, XOR swizzle bits 4-6)
#pragma unroll
    for (int nf = 0; nf < 8; ++nf) {
        int n = nf * 16 + g * 4;
        int byr = (mloc * 512 + n * 2) ^ ((mloc & 7) << 4);
        ushort4 ur, us;
        ur.x = f2h(rr[nf][0]); ur.y = f2h(rr[nf][1]);
        ur.z = f2h(rr[nf][2]); ur.w = f2h(rr[nf][3]);
        us.x = f2h(sv[nf][0]); us.y = f2h(sv[nf][1]);
        us.z = f2h(sv[nf][2]); us.w = f2h(sv[nf][3]);
        *(ushort4*)((char*)tile + byr) = ur;
        *(ushort4*)((char*)tile + byr + 256) = us;
    }
    __syncthreads();

    // stage 2: (r|s) @ catW^T, K=256
    f32x4 acc2[8] = {};
#pragma unroll
    for (int k0 = 0; k0 < 256; k0 += 32) {
        int kk = k0 + g * 8;
        int by = (mloc * 512 + kk * 2) ^ ((mloc & 7) << 4);
        f16x8 bf = *(const f16x8*)((const char*)tile + by);
#pragma unroll
        for (int nf = 0; nf < 8; ++nf) {
            f16x8 af = *(const f16x8*)(kWt + (size_t)(nf * 16 + ln) * 256 + kk);
            acc2[nf] = __builtin_amdgcn_mfma_f32_16x16x32_f16(af, bf, acc2[nf], 0, 0, 0);
        }
    }

    // LN epilogue
    float x[8][4];
    float sum = 0.f, ssum = 0.f;
#pragma unroll
    for (int nf = 0; nf < 8; ++nf) {
        float4 b = *(const float4*)(cbias + nf * 16 + g * 4);
        f32x4 vv = acc2[nf];
        x[nf][0] = vv[0] + b.x; x[nf][1] = vv[1] + b.y;
        x[nf][2] = vv[2] + b.z; x[nf][3] = vv[3] + b.w;
        sum += x[nf][0] + x[nf][1] + x[nf][2] + x[nf][3];
        ssum += x[nf][0] * x[nf][0] + x[nf][1] * x[nf][1]
              + x[nf][2] * x[nf][2] + x[nf][3] * x[nf][3];
    }
    sum  += __shfl_xor(sum, 16, 64);  sum  += __shfl_xor(sum, 32, 64);
    ssum += __shfl_xor(ssum, 16, 64); ssum += __shfl_xor(ssum, 32, 64);
    float mu = sum * (1.0f / 128.0f);
    float var = ssum * (1.0f / 128.0f) - mu * mu;
    float inv = rsqrtf(var + LN_EPS);
    if (vm) {
        float* op = out + (size_t)m * 128 + g * 4;
#pragma unroll
        for (int nf = 0; nf < 8; ++nf) {
            float4 gv = *(const float4*)(gam + nf * 16 + g * 4);
            float4 ev = *(const float4*)(bet + nf * 16 + g * 4);
            float4 o;
            o.x = (x[nf][0] - mu) * inv * gv.x + ev.x;
            o.y = (x[nf][1] - mu) * inv * gv.y + ev.y;
            o.z = (x[nf][2] - mu) * inv * gv.z + ev.z;
            o.w = (x[nf][3] - mu) * inv * gv.w + ev.w;
            *(float4*)(op + nf * 16) = o;
        }
    }
}

__global__ void k_ws_too_small(float* out) {
    if (threadIdx.x == 0 && blockIdx.x == 0) out[0] = 12345678.f;
}

// ---------------- orchestration ----------------

struct Lvl {
    int n, E;
    const int *src, *dst;
    int *cnt_out, *cnt_in, *ptr, *cursor, *eid, *srcs;
    float *rout, *rin;
};

static inline char* bump(char*& p, size_t bytes, void** out) {
    *out = (void*)p;
    p += (bytes + 255) & ~(size_t)255;
    return p;
}

extern "C" void kernel_launch(void* const* d_in, const int* in_sizes, int n_in,
                              void* d_out, int out_size, void* d_ws, size_t ws_size,
                              hipStream_t stream) {
    const float* h0 = (const float*)d_in[0];
    const float* h1 = (const float*)d_in[1];
    const float* h2 = (const float*)d_in[2];
    const int* src0 = (const int*)d_in[3];
    const int* dst0 = (const int*)d_in[4];
    const int* src1 = (const int*)d_in[5];
    const int* dst1 = (const int*)d_in[6];
    const int* src2 = (const int*)d_in[7];
    const int* dst2 = (const int*)d_in[8];
    const float* convW = (const float*)d_in[9];
    const float* convb = (const float*)d_in[10];
    const float* fusW  = (const float*)d_in[11];
    const float* fusb  = (const float*)d_in[12];
    const float* catW  = (const float*)d_in[13];
    const float* catb  = (const float*)d_in[14];
    const float* convw = (const float*)d_in[15];
    const float* tdw   = (const float*)d_in[16];
    const float* buw   = (const float*)d_in[17];
    const float* lng   = (const float*)d_in[18];
    const float* lnb   = (const float*)d_in[19];
    float* out = (float*)d_out;

    // workspace carve-out
    char* p = (char*)d_ws;
    void *vh0f, *vh1f, *vh2f, *vXf, *vAa, *vAb, *vAc, *vsWt, *vkWt, *vbsum;
    bump(p, (size_t)cN0 * D * 2, &vh0f);
    bump(p, (size_t)cN1 * D * 2, &vh1f);
    bump(p, (size_t)cN2 * D * 2, &vh2f);
    bump(p, (size_t)cN1 * D * 2, &vXf);
    bump(p, (size_t)cN2 * D * 2, &vAa);
    bump(p, (size_t)cN2 * D * 2, &vAb);
    bump(p, (size_t)cN1 * D * 2, &vAc);
    bump(p, (size_t)7 * 16384 * 2, &vsWt);
    bump(p, (size_t)3 * 32768 * 2, &vkWt);
    bump(p, 512 * 4, &vbsum);
    unsigned short* h0f = (unsigned short*)vh0f;
    unsigned short* h1f = (unsigned short*)vh1f;
    unsigned short* h2f = (unsigned short*)vh2f;
    unsigned short* Xf  = (unsigned short*)vXf;
    unsigned short* Aa  = (unsigned short*)vAa;
    unsigned short* Ab  = (unsigned short*)vAb;
    unsigned short* Ac  = (unsigned short*)vAc;
    unsigned short* sWt = (unsigned short*)vsWt;
    unsigned short* kWt = (unsigned short*)vkWt;
    int* bsum = (int*)vbsum;

    Lvl lv[3];
    lv[0] = {cN0, cE0, src0, dst0};
    lv[1] = {cN1, cE1, src1, dst1};
    lv[2] = {cN2, cE2, src2, dst2};
    for (int L = 0; L < 3; ++L) {
        Lvl& v = lv[L];
        void* t;
        bump(p, (size_t)v.n * 4, &t);       v.cnt_out = (int*)t;
        bump(p, (size_t)v.n * 4, &t);       v.cnt_in  = (int*)t;
        bump(p, (size_t)(v.n + 1) * 4, &t); v.ptr     = (int*)t;
        bump(p, (size_t)v.n * 4, &t);       v.cursor  = (int*)t;
        bump(p, (size_t)v.E * 4, &t);       v.eid     = (int*)t;
        bump(p, (size_t)v.E * 4, &t);       v.srcs    = (int*)t;
        bump(p, (size_t)v.n * 4, &t);       v.rout    = (float*)t;
        bump(p, (size_t)v.n * 4, &t);       v.rin     = (float*)t;
    }
    size_t need = (size_t)(p - (char*)d_ws);
    if (need > ws_size) {
        hipLaunchKernelGGL(k_ws_too_small, dim3(1), dim3(64), 0, stream, out);
        return;
    }

    // prep: weights (transpose + cw-fold + f16) and h -> f16
    k_prep_w<<<832, 256, 0, stream>>>(convW, fusW, catW, convw, tdw, buw, sWt, kWt);
    k_f2h<<<(cN0 * D / 4 + 255) / 256, 256, 0, stream>>>(h0, h0f, cN0 * D / 4);
    k_f2h<<<(cN1 * D / 4 + 255) / 256, 256, 0, stream>>>(h1, h1f, cN1 * D / 4);
    k_f2h<<<(cN2 * D / 4 + 255) / 256, 256, 0, stream>>>(h2, h2f, cN2 * D / 4);

    for (int L = 0; L < 3; ++L) {
        Lvl& v = lv[L];
        hipMemsetAsync(v.cnt_out, 0, (size_t)v.n * 4, stream);
        hipMemsetAsync(v.cnt_in, 0, (size_t)v.n * 4, stream);
        k_count<<<(v.E + 255) / 256, 256, 0, stream>>>(v.src, v.dst, v.cnt_out, v.cnt_in, v.E);
        int nb = (v.n + 1023) / 1024;
        k_bsum<<<nb, 256, 0, stream>>>(v.cnt_in, bsum, v.n);
        k_scan_write<<<nb, 256, 0, stream>>>(v.cnt_in, bsum, v.ptr, v.n, v.E);
        k_rin_cursor<<<(v.n + 255) / 256, 256, 0, stream>>>(v.cnt_out, v.cnt_in, v.ptr,
                                                            v.rout, v.rin, v.cursor, v.n);
        k_fill<<<(v.E + 255) / 256, 256, 0, stream>>>(v.src, v.dst, v.cursor, v.eid, v.srcs, v.E);
    }

    // ---- level 0 (params idx 0): terms [conv(h0), td(segsum h1)] ----
    {
        Lvl& v = lv[0];
        k_segsum_h<<<(cN0 + 3) / 4, 256, 0, stream>>>(Xf, v.ptr, v.eid, h1f, cN0);
        k_aggh<2, false><<<(cN0 * 32 + 255) / 256, 256, 0, stream>>>(
            h0f, Xf, Xf, nullptr, v.rout, v.ptr, v.srcs, Aa, Ab, Ab, cN0);
        k_mega<2><<<(cN0 + 63) / 64, 256, 0, stream>>>(
            Aa, Ab, Ab,
            sWt + 0 * 16384, sWt + 1 * 16384, sWt,
            convb, convw, fusb, tdw, convb, convw,
            v.rin, kWt, catb, lng, lnb, out, cN0);
    }

    // ---- level 1 (params idx 2): terms [conv(h1), bu(h0[dst0]), td(segsum h2)] ----
    {
        Lvl& v = lv[1];
        const int o1 = 2 * D;
        k_segsum_h<<<(cN1 + 3) / 4, 256, 0, stream>>>(Xf, v.ptr, v.eid, h2f, cN1);
        k_aggh<3, true><<<(cN1 * 32 + 255) / 256, 256, 0, stream>>>(
            h1f, h0f, Xf, dst0, v.rout, v.ptr, v.srcs, Aa, Ab, Ac, cN1);
        k_mega<3><<<(cN1 + 63) / 64, 256, 0, stream>>>(
            Aa, Ab, Ac,
            sWt + 2 * 16384, sWt + 3 * 16384, sWt + 4 * 16384,
            convb + o1, convw + o1, fusb + o1, buw + o1, fusb + o1, tdw + o1,
            v.rin, kWt + 2 * 32768, catb + o1, lng + o1, lnb + o1,
            out + (size_t)cN0 * D, cN1);
    }

    // ---- level 2 (params idx 1): terms [conv(h2), bu(h1[dst1])] ----
    {
        Lvl& v = lv[2];
        const int o1 = 1 * D;
        k_aggh<2, true><<<(cN2 * 32 + 255) / 256, 256, 0, stream>>>(
            h2f, h1f, h1f, dst1, v.rout, v.ptr, v.srcs, Aa, Ab, Ab, cN2);
        k_mega<2><<<(cN2 + 63) / 64, 256, 0, stream>>>(
            Aa, Ab, Ab,
            sWt + 5 * 16384, sWt + 6 * 16384, sWt,
            convb + o1, convw + o1, fusb + o1, buw + o1, convb + o1, convw + o1,
            v.rin, kWt + 1 * 32768, catb + o1, lng + o1, lnb + o1,
            out + (size_t)(cN0 + cN1) * D, cN2);
    }
}